// Round 1
// 371.534 us; speedup vs baseline: 1.1016x; 1.1016x over previous
//
#include <hip/hip_runtime.h>
#include <hip/hip_fp16.h>

// GCN: N=100000, E=1600000, widths 128 -> 16 -> 64 -> 128 -> 1
// Round 12: fp16 STORAGE for intermediate feature maps A (16ch), B (16ch),
// C (64ch). All math (accumulation, GEMMs) stays fp32 -- only the gathered
// operands are compressed. gather64's per-edge pull drops 256B (2 lines) ->
// 128B (1 line); A/B drop to 3.2MB (< 4MiB/XCD L2 -> near-resident).
// Vectorization preserved: gather64 = 8 lanes x uint4 per row (1 vmem instr
// per 8 edges), gather16 = 4 lanes x uint2 per row (1 instr per 16 edges).
// Pipeline: hist_rank -> scan(+dinv) -> fill+gemm1 -> gather16(r1)
//           -> g16gemm2(r2) -> gather64 -> head.

#define NN 100000
#define NE 1600000
#define NB ((NN + 255) / 256)   // 391 blocks for scans

__device__ __forceinline__ float rdl_f(float v, int l) {
    return __int_as_float(__builtin_amdgcn_readlane(__float_as_int(v), l));
}

// unpack one half2 word, accumulate into two fp32 lanes
__device__ __forceinline__ void h2acc(unsigned u, float& a, float& b) {
    __half2 h = *reinterpret_cast<__half2*>(&u);
    float2 f = __half22float2(h);
    a += f.x; b += f.y;
}
__device__ __forceinline__ unsigned packh2(float a, float b) {
    __half2 h = __floats2half2_rn(a, b);
    return *reinterpret_cast<unsigned*>(&h);
}

// ---------------- histogram + rank ----------------
__global__ void hist_rank_k(const int* __restrict__ dst, int* __restrict__ ideg,
                            int* __restrict__ rank, int e) {
    int i = blockIdx.x * blockDim.x + threadIdx.x;
    if (i < e) rank[i] = atomicAdd(&ideg[dst[i]], 1);
}

// ---------------- scan pass 1 (+ fused dinv) ----------------
__global__ void scan_reduce_k(const int* __restrict__ ideg, int* __restrict__ bsum,
                              float* __restrict__ dinv, int n) {
    __shared__ int s[256];
    int i = blockIdx.x * 256 + threadIdx.x;
    int v = (i < n) ? ideg[i] : 0;
    if (i < n) dinv[i] = rsqrtf((float)v + 1.0f);  // +1 self loop
    s[threadIdx.x] = v;
    __syncthreads();
    for (int off = 128; off > 0; off >>= 1) {
        if (threadIdx.x < off) s[threadIdx.x] += s[threadIdx.x + off];
        __syncthreads();
    }
    if (threadIdx.x == 0) bsum[blockIdx.x] = s[0];
}

__global__ __launch_bounds__(512) void scan_partials_k(const int* __restrict__ bsum,
                                                       int* __restrict__ bofs, int nb) {
    __shared__ int s[512];
    int t = threadIdx.x;
    int v = (t < nb) ? bsum[t] : 0;
    s[t] = v;
    __syncthreads();
    for (int off = 1; off < 512; off <<= 1) {
        int a = (t >= off) ? s[t - off] : 0;
        __syncthreads();
        s[t] += a;
        __syncthreads();
    }
    if (t < nb) bofs[t] = s[t] - v;  // exclusive
}

__global__ void scan_final_k(const int* __restrict__ ideg, const int* __restrict__ bofs,
                             int* __restrict__ rowptr, int n, int e) {
    __shared__ int s[256];
    int i = blockIdx.x * 256 + threadIdx.x;
    int t = threadIdx.x;
    int v = (i < n) ? ideg[i] : 0;
    s[t] = v;
    __syncthreads();
    for (int off = 1; off < 256; off <<= 1) {
        int a = (t >= off) ? s[t - off] : 0;
        __syncthreads();
        s[t] += a;
        __syncthreads();
    }
    int excl = s[t] - v + bofs[blockIdx.x];
    if (i < n) rowptr[i] = excl;
    if (i == 0) rowptr[n] = e;
}

// ---------------- fused: CSR fill (blocks < fillBlocks) + gemm1 (rest) ----------------
// gemm1: A = dinv * (x @ W1), K=128, M=16, output stored fp16.
__global__ __launch_bounds__(256) void fill_gemm1_k(const int* __restrict__ src,
                                                    const int* __restrict__ dst,
                                                    const int* __restrict__ rank,
                                                    const int* __restrict__ rowptr,
                                                    int* __restrict__ csr_src,
                                                    const float* __restrict__ x,
                                                    const float* __restrict__ W1,
                                                    const float* __restrict__ dinv,
                                                    __half* __restrict__ A,
                                                    int e, int n, int fillBlocks) {
    __shared__ float sW[128 * 16];
    __shared__ float sIn[16][132];           // +4 pad
    if ((int)blockIdx.x < fillBlocks) {
        int i = blockIdx.x * 256 + threadIdx.x;
        if (i < e) csr_src[rowptr[dst[i]] + rank[i]] = src[i];
        return;
    }
    const int bid = blockIdx.x - fillBlocks;
    const int tid = threadIdx.x;
    for (int i = tid; i < 128 * 16; i += 256) sW[i] = W1[i];
    const int row0 = bid * 16;
    const float4* in4 = (const float4*)x;
    for (int i = tid; i < 16 * 32; i += 256) {
        int r = i >> 5, kv = i & 31;
        int g = row0 + r;
        float4 v = make_float4(0.f, 0.f, 0.f, 0.f);
        if (g < n) v = in4[(long)g * 32 + kv];
        ((float4*)&sIn[r][0])[kv] = v;
    }
    __syncthreads();
    const int r = tid >> 4, m = tid & 15;
    const int g = row0 + r;
    if (g < n) {
        float acc = 0.0f;
#pragma unroll
        for (int k = 0; k < 128; ++k) acc += sIn[r][k] * sW[k * 16 + m];
        A[(long)g * 16 + m] = __float2half(acc * dinv[g]);
    }
}

// ---------------- pull-gather, 16 ch fp16: B = dinv*relu(dg*(sum A)+b1) ----------------
// 4 lanes x uint2 (8B) per 32B row; 16 edge subgroups per wave.
__global__ __launch_bounds__(256) void gather16h_k(const int* __restrict__ rowptr,
                                                   const int* __restrict__ csr_src,
                                                   const float* __restrict__ dinv,
                                                   const __half* __restrict__ hs,
                                                   const float* __restrict__ bias,
                                                   __half* __restrict__ outp, int n) {
    const int g = (blockIdx.x * 256 + threadIdx.x) >> 6;
    if (g >= n) return;
    const int lane = threadIdx.x & 63;
    const int q = lane & 3;                 // uint2 chunk within 16-ch row
    const int sub = lane >> 2;              // edge subgroup 0..15
    const float dg = dinv[g];
    const int beg = rowptr[g], end = rowptr[g + 1];
    const uint2* h2p = (const uint2*)hs;
    float a0 = 0.f, a1 = 0.f, a2 = 0.f, a3 = 0.f;
    if (sub == 0) {                          // self term
        uint2 v = h2p[(long)g * 4 + q];
        h2acc(v.x, a0, a1); h2acc(v.y, a2, a3);
    }
    for (int j0 = beg; j0 < end; j0 += 16) {
        int idx = j0 + sub;
        if (idx < end) {
            const int s = csr_src[idx];
            uint2 v = h2p[(long)s * 4 + q];
            h2acc(v.x, a0, a1); h2acc(v.y, a2, a3);
        }
    }
#pragma unroll
    for (int m = 4; m <= 32; m <<= 1) {
        a0 += __shfl_xor(a0, m, 64);
        a1 += __shfl_xor(a1, m, 64);
        a2 += __shfl_xor(a2, m, 64);
        a3 += __shfl_xor(a3, m, 64);
    }
    if (sub == 0) {
        const float4 b = ((const float4*)bias)[q];
        float v0 = fmaxf(fmaf(dg, a0, b.x), 0.0f) * dg;
        float v1 = fmaxf(fmaf(dg, a1, b.y), 0.0f) * dg;
        float v2 = fmaxf(fmaf(dg, a2, b.z), 0.0f) * dg;
        float v3 = fmaxf(fmaf(dg, a3, b.w), 0.0f) * dg;
        uint2 w;
        w.x = packh2(v0, v1);
        w.y = packh2(v2, v3);
        ((uint2*)outp)[(long)g * 4 + q] = w;
    }
}

// ---------------- fused gather16 + gemm2: C = dinv*relu(dg*(sum B)@W2 + b2), fp16 out ----
__global__ __launch_bounds__(256) void g16gemm2h_k(const int* __restrict__ rowptr,
                                                   const int* __restrict__ csr_src,
                                                   const float* __restrict__ dinv,
                                                   const __half* __restrict__ hs,
                                                   const float* __restrict__ W2,
                                                   const float* __restrict__ b2,
                                                   __half* __restrict__ outp, int n) {
    const int lane = threadIdx.x & 63;
    const int wid = blockIdx.x * 4 + (threadIdx.x >> 6);
    const int nWaves = gridDim.x * 4;
    float w2[16];
#pragma unroll
    for (int k = 0; k < 16; ++k) w2[k] = W2[k * 64 + lane];
    const float bm = b2[lane];
    const int q = lane & 3;
    const int sub = lane >> 2;
    const uint2* h2p = (const uint2*)hs;
    for (int g = wid; g < n; g += nWaves) {
        const float dg = dinv[g];
        const int beg = rowptr[g], end = rowptr[g + 1];
        float a0 = 0.f, a1 = 0.f, a2 = 0.f, a3 = 0.f;
        if (sub == 0) {                      // self term
            uint2 v = h2p[(long)g * 4 + q];
            h2acc(v.x, a0, a1); h2acc(v.y, a2, a3);
        }
        for (int j0 = beg; j0 < end; j0 += 16) {
            int idx = j0 + sub;
            if (idx < end) {
                const int s = csr_src[idx];
                uint2 v = h2p[(long)s * 4 + q];
                h2acc(v.x, a0, a1); h2acc(v.y, a2, a3);
            }
        }
#pragma unroll
        for (int m = 4; m <= 32; m <<= 1) {
            a0 += __shfl_xor(a0, m, 64);
            a1 += __shfl_xor(a1, m, 64);
            a2 += __shfl_xor(a2, m, 64);
            a3 += __shfl_xor(a3, m, 64);
        }
        float t = 0.0f;
#pragma unroll
        for (int ql = 0; ql < 4; ++ql) {
            t = fmaf(rdl_f(a0, ql), w2[4 * ql + 0], t);
            t = fmaf(rdl_f(a1, ql), w2[4 * ql + 1], t);
            t = fmaf(rdl_f(a2, ql), w2[4 * ql + 2], t);
            t = fmaf(rdl_f(a3, ql), w2[4 * ql + 3], t);
        }
        float r = fmaxf(fmaf(dg, t, bm), 0.0f);   // dg*(sum)@W2 + b2, relu
        outp[(long)g * 64 + lane] = __float2half(r * dg);  // pre-scaled fp16
    }
}

// ---------------- pull-gather, 64 ch fp16: aggS2 = dg * sum C ----------------
// 8 lanes x uint4 (16B) per 128B row (exactly one cache line per edge).
__global__ __launch_bounds__(256) void gather64h_k(const int* __restrict__ rowptr,
                                                   const int* __restrict__ csr_src,
                                                   const float* __restrict__ dinv,
                                                   const __half* __restrict__ hs,
                                                   float* __restrict__ outp, int n) {
    const int g = (blockIdx.x * 256 + threadIdx.x) >> 6;
    if (g >= n) return;
    const int lane = threadIdx.x & 63;
    const int q = lane & 7;                 // uint4 chunk within 64-ch row
    const int sub = lane >> 3;              // edge subgroup 0..7
    const float dg = dinv[g];
    const int beg = rowptr[g], end = rowptr[g + 1];
    const uint4* h4 = (const uint4*)hs;     // row = 8 chunks of 16B
    float a[8];
#pragma unroll
    for (int i = 0; i < 8; ++i) a[i] = 0.f;
    if (sub == 0) {                          // self term
        uint4 v = h4[(long)g * 8 + q];
        h2acc(v.x, a[0], a[1]); h2acc(v.y, a[2], a[3]);
        h2acc(v.z, a[4], a[5]); h2acc(v.w, a[6], a[7]);
    }
    int j0 = beg;
    for (; j0 + 16 <= end; j0 += 16) {
        const int s0 = csr_src[j0 + sub];
        const int s1 = csr_src[j0 + 8 + sub];
        const uint4 v0 = h4[(long)s0 * 8 + q];
        const uint4 v1 = h4[(long)s1 * 8 + q];
        h2acc(v0.x, a[0], a[1]); h2acc(v0.y, a[2], a[3]);
        h2acc(v0.z, a[4], a[5]); h2acc(v0.w, a[6], a[7]);
        h2acc(v1.x, a[0], a[1]); h2acc(v1.y, a[2], a[3]);
        h2acc(v1.z, a[4], a[5]); h2acc(v1.w, a[6], a[7]);
    }
    for (; j0 < end; j0 += 8) {
        int idx = j0 + sub;
        if (idx < end) {
            const int s = csr_src[idx];
            const uint4 v = h4[(long)s * 8 + q];
            h2acc(v.x, a[0], a[1]); h2acc(v.y, a[2], a[3]);
            h2acc(v.z, a[4], a[5]); h2acc(v.w, a[6], a[7]);
        }
    }
#pragma unroll
    for (int m = 8; m <= 32; m <<= 1) {
#pragma unroll
        for (int i = 0; i < 8; ++i) a[i] += __shfl_xor(a[i], m, 64);
    }
    if (sub == 0) {
        float4* o4 = (float4*)(outp + (long)g * 64 + q * 8);
        o4[0] = make_float4(a[0] * dg, a[1] * dg, a[2] * dg, a[3] * dg);
        o4[1] = make_float4(a[4] * dg, a[5] * dg, a[6] * dg, a[7] * dg);
    }
}

// ---------------- zero-LDS head: W3 in VGPRs, readlane broadcast ----------------
__global__ __launch_bounds__(256) void head_k(const float* __restrict__ aggS2,
                                              const float* __restrict__ W3,
                                              const float* __restrict__ b3,
                                              const float* __restrict__ Wfc,
                                              const float* __restrict__ bfc,
                                              float* __restrict__ out, int n) {
    const int lane = threadIdx.x & 63;
    const int wid = blockIdx.x * 4 + (threadIdx.x >> 6);
    const int nWaves = gridDim.x * 4;
    float w0[64], w1[64];
#pragma unroll
    for (int k = 0; k < 64; ++k) {
        w0[k] = W3[k * 128 + lane];
        w1[k] = W3[k * 128 + lane + 64];
    }
    const float bm0 = b3[lane], bm1 = b3[lane + 64];
    const float wf0 = Wfc[lane], wf1 = Wfc[lane + 64];
    const float bb = bfc[0];
    for (int g0 = wid * 4; g0 < n; g0 += nWaves * 4) {
        const float* base = aggS2 + (long)g0 * 64 + lane;
        const float rv0 = base[0];
        const float rv1 = base[64];
        const float rv2 = base[128];
        const float rv3 = base[192];
        float a00 = 0.f, a01 = 0.f, a10 = 0.f, a11 = 0.f;
        float a20 = 0.f, a21 = 0.f, a30 = 0.f, a31 = 0.f;
#pragma unroll
        for (int k = 0; k < 64; ++k) {
            const float x0 = rdl_f(rv0, k);
            const float x1 = rdl_f(rv1, k);
            const float x2 = rdl_f(rv2, k);
            const float x3 = rdl_f(rv3, k);
            a00 = fmaf(x0, w0[k], a00); a01 = fmaf(x0, w1[k], a01);
            a10 = fmaf(x1, w0[k], a10); a11 = fmaf(x1, w1[k], a11);
            a20 = fmaf(x2, w0[k], a20); a21 = fmaf(x2, w1[k], a21);
            a30 = fmaf(x3, w0[k], a30); a31 = fmaf(x3, w1[k], a31);
        }
        float v0 = fmaxf(a00 + bm0, 0.f) * wf0 + fmaxf(a01 + bm1, 0.f) * wf1;
        float v1 = fmaxf(a10 + bm0, 0.f) * wf0 + fmaxf(a11 + bm1, 0.f) * wf1;
        float v2 = fmaxf(a20 + bm0, 0.f) * wf0 + fmaxf(a21 + bm1, 0.f) * wf1;
        float v3 = fmaxf(a30 + bm0, 0.f) * wf0 + fmaxf(a31 + bm1, 0.f) * wf1;
#pragma unroll
        for (int off = 32; off > 0; off >>= 1) {
            v0 += __shfl_down(v0, off, 64);
            v1 += __shfl_down(v1, off, 64);
            v2 += __shfl_down(v2, off, 64);
            v3 += __shfl_down(v3, off, 64);
        }
        if (lane == 0)
            ((float4*)out)[g0 >> 2] = make_float4(v0 + bb, v1 + bb, v2 + bb, v3 + bb);
    }
}

extern "C" void kernel_launch(void* const* d_in, const int* in_sizes, int n_in,
                              void* d_out, int out_size, void* d_ws, size_t ws_size,
                              hipStream_t stream) {
    const float* x    = (const float*)d_in[0];
    const int*   ei   = (const int*)d_in[1];       // [2,E]: src = ei, dst = ei+E
    const float* W1   = (const float*)d_in[2];
    const float* b1   = (const float*)d_in[3];
    const float* W2   = (const float*)d_in[4];
    const float* b2   = (const float*)d_in[5];
    const float* W3   = (const float*)d_in[6];
    const float* b3   = (const float*)d_in[7];
    const float* Wfc  = (const float*)d_in[8];
    const float* bfc  = (const float*)d_in[9];
    float* out = (float*)d_out;

    const int* src = ei;
    const int* dst = ei + NE;

    // workspace layout (16B-aligned offsets):
    // dinv[N] f32 | ideg[N] | rowptr[N+8] | bsum[512] | bofs[512] | rank[E]
    // | csr_src[E+64] | A_h[16N] fp16 | B_h[16N] fp16 | C_h[64N] fp16 | aggS2[64N] f32
    float* dinv    = (float*)d_ws;
    int*   ideg    = (int*)(dinv + NN);
    int*   rowptr  = ideg + NN;
    int*   bsum    = rowptr + NN + 8;
    int*   bofs    = bsum + 512;
    int*   rank    = bofs + 512;
    int*   csr_src = rank + NE;
    __half* A_h    = (__half*)(csr_src + NE + 64);
    __half* B_h    = A_h + (long)NN * 16;
    __half* C_h    = B_h + (long)NN * 16;
    float* aggS2   = (float*)(C_h + (long)NN * 64);

    const int T = 256;

    // ---- CSR + norm build ----
    hipMemsetAsync(ideg, 0, NN * sizeof(int), stream);
    hist_rank_k<<<(NE + T - 1) / T, T, 0, stream>>>(dst, ideg, rank, NE);
    scan_reduce_k<<<NB, T, 0, stream>>>(ideg, bsum, dinv, NN);
    scan_partials_k<<<1, 512, 0, stream>>>(bsum, bofs, NB);
    scan_final_k<<<NB, T, 0, stream>>>(ideg, bofs, rowptr, NN, NE);

    // ---- fused: CSR fill + gemm1 (A = dinv * x@W1, 16ch fp16) ----
    const int fillBlocks = (NE + T - 1) / T;           // 6250
    const int gemmBlocks = (NN + 15) / 16;             // 6250
    fill_gemm1_k<<<fillBlocks + gemmBlocks, T, 0, stream>>>(
        src, dst, rank, rowptr, csr_src, x, W1, dinv, A_h, NE, NN, fillBlocks);

    // ---- B = dinv * relu(dg*(sum A) + b1)  (pre-scaled r1, 16ch fp16) ----
    gather16h_k<<<(NN + 3) / 4, T, 0, stream>>>(rowptr, csr_src, dinv, A_h, b1, B_h, NN);
    // ---- C = dinv * relu(dg*(sum B)@W2 + b2)  (pre-scaled r2, 64ch fp16) ----
    g16gemm2h_k<<<3072, T, 0, stream>>>(rowptr, csr_src, dinv, B_h, W2, b2, C_h, NN);
    // ---- aggS2(64ch f32) = dg * sum C ----
    gather64h_k<<<(NN + 3) / 4, T, 0, stream>>>(rowptr, csr_src, dinv, C_h, aggS2, NN);
    // ---- head: out = relu(aggS2@W3 + b3).Wfc + bfc ----
    head_k<<<2048, T, 0, stream>>>(aggS2, W3, b3, Wfc, bfc, out, NN);
}

// Round 2
// 326.795 us; speedup vs baseline: 1.2524x; 1.1369x over previous
//
#include <hip/hip_runtime.h>
#include <hip/hip_fp16.h>

// GCN: N=100000, E=1600000, widths 128 -> 16 -> 64 -> 128 -> 1
// Round 13: replace atomic hist_rank (67us, memory-side atomic serialization:
// 1.6M global atomicAdd-with-return = 24/ns ceiling, 51MB RMW write traffic)
// with a deterministic two-level bucket CSR build (zero global atomics):
//   P1: per-block LDS histogram into 782 buckets (dst>>7), counts -> mat
//       (fused with gemm1_raw = x@W1 unscaled, which depends on nothing)
//   colscan/basescan: exclusive scans -> per-(block,bucket) slot bases
//   P2: replay edges, LDS cursors, scatter (src, dst&127) into bucket regions
//   P3: per-bucket (128 nodes, ~2k edges) LDS hist + scan -> rowptr/dinv,
//       scatter csr_src into 16KB window; rescale A by dinv in-place.
// Also deletes rank[] (12.8MB traffic) and the old 3-kernel scan.
// Intermediates A/B/C stored fp16 (R12); all math fp32.
// Pipeline: count+gemm1 -> colscan -> basescan -> p2 -> p3
//           -> gather16(r1) -> g16gemm2(r2) -> gather64 -> head.

#define NN 100000
#define NE 1600000
#define SHIFT 7                      // 128 nodes per bucket
#define NB2 782                      // ceil(NN/128)
#define EPB 2048                     // edges per P1/P2 block
#define NBLK 782                     // ceil(NE/EPB)
#define CHUNK 13                     // ceil(NBLK/64) for colscan

__device__ __forceinline__ float rdl_f(float v, int l) {
    return __int_as_float(__builtin_amdgcn_readlane(__float_as_int(v), l));
}

// unpack one half2 word, accumulate into two fp32 lanes
__device__ __forceinline__ void h2acc(unsigned u, float& a, float& b) {
    __half2 h = *reinterpret_cast<__half2*>(&u);
    float2 f = __half22float2(h);
    a += f.x; b += f.y;
}
__device__ __forceinline__ unsigned packh2(float a, float b) {
    __half2 h = __floats2half2_rn(a, b);
    return *reinterpret_cast<unsigned*>(&h);
}
__device__ __forceinline__ unsigned sc2(unsigned u, float s) {
    __half2 h = *reinterpret_cast<__half2*>(&u);
    float2 f = __half22float2(h);
    return packh2(f.x * s, f.y * s);
}

// ---------------- P1: bucket counts (blocks < NBLK) + gemm1_raw (rest) ----------------
// gemm1_raw: A = x @ W1 (unscaled; dinv applied in P3), K=128, M=16, fp16 out.
__global__ __launch_bounds__(256) void count_gemm1_k(const int* __restrict__ dst,
                                                     int* __restrict__ mat,
                                                     const float* __restrict__ x,
                                                     const float* __restrict__ W1,
                                                     __half* __restrict__ A, int n) {
    __shared__ int cnt[NB2];
    __shared__ float sW[128 * 16];
    __shared__ float sIn[16][132];           // +4 pad
    const int tid = threadIdx.x;
    if ((int)blockIdx.x < NBLK) {
        for (int i = tid; i < NB2; i += 256) cnt[i] = 0;
        __syncthreads();
        const int e0 = blockIdx.x * EPB;
        const int e1 = min(e0 + EPB, NE);
        for (int i = e0 + tid; i < e1; i += 256) atomicAdd(&cnt[dst[i] >> SHIFT], 1);
        __syncthreads();
        for (int c = tid; c < NB2; c += 256) mat[blockIdx.x * NB2 + c] = cnt[c];
        return;
    }
    const int bid = blockIdx.x - NBLK;
    for (int i = tid; i < 128 * 16; i += 256) sW[i] = W1[i];
    const int row0 = bid * 16;
    const float4* in4 = (const float4*)x;
    for (int i = tid; i < 16 * 32; i += 256) {
        int r = i >> 5, kv = i & 31;
        int g = row0 + r;
        float4 v = make_float4(0.f, 0.f, 0.f, 0.f);
        if (g < n) v = in4[(long)g * 32 + kv];
        ((float4*)&sIn[r][0])[kv] = v;
    }
    __syncthreads();
    const int r = tid >> 4, m = tid & 15;
    const int g = row0 + r;
    if (g < n) {
        float acc = 0.0f;
#pragma unroll
        for (int k = 0; k < 128; ++k) acc += sIn[r][k] * sW[k * 16 + m];
        A[(long)g * 16 + m] = __float2half(acc);
    }
}

// ---------------- colscan: per-bucket exclusive scan over edge-blocks ----------------
// mat[b][c] (row-major) -> ofsT[b][c] = sum_{b'<b} mat[b'][c]; colTotal[c].
__global__ __launch_bounds__(64) void colscan_k(const int* __restrict__ mat,
                                                int* __restrict__ ofsT,
                                                int* __restrict__ colTotal) {
    const int c = blockIdx.x;
    const int lane = threadIdx.x;
    int v[CHUNK];
    int s = 0;
    const int base = lane * CHUNK;
#pragma unroll
    for (int j = 0; j < CHUNK; ++j) {
        int b = base + j;
        int x_ = (b < NBLK) ? mat[b * NB2 + c] : 0;
        v[j] = s;              // local exclusive prefix
        s += x_;
    }
    // wave exclusive scan of chunk sums
    int inc = s;
#pragma unroll
    for (int d = 1; d < 64; d <<= 1) {
        int t = __shfl_up(inc, d, 64);
        if (lane >= d) inc += t;
    }
    const int excl = inc - s;
#pragma unroll
    for (int j = 0; j < CHUNK; ++j) {
        int b = base + j;
        if (b < NBLK) ofsT[b * NB2 + c] = excl + v[j];
    }
    if (lane == 63) colTotal[c] = excl + s;
}

// ---------------- basescan: exclusive scan of bucket totals ----------------
__global__ __launch_bounds__(1024) void basescan_k(const int* __restrict__ colTotal,
                                                   int* __restrict__ bucketBase,
                                                   int* __restrict__ rowptr) {
    __shared__ int s[1024];
    const int t = threadIdx.x;
    int v = (t < NB2) ? colTotal[t] : 0;
    s[t] = v;
    __syncthreads();
    for (int off = 1; off < 1024; off <<= 1) {
        int a = (t >= off) ? s[t - off] : 0;
        __syncthreads();
        s[t] += a;
        __syncthreads();
    }
    if (t < NB2) bucketBase[t] = s[t] - v;  // exclusive
    if (t == 0) { bucketBase[NB2] = NE; rowptr[NN] = NE; }
}

// ---------------- P2: scatter edges into bucket regions (LDS cursors) ----------------
__global__ __launch_bounds__(256) void p2_scatter_k(const int* __restrict__ src,
                                                    const int* __restrict__ dst,
                                                    const int* __restrict__ ofsT,
                                                    const int* __restrict__ bucketBase,
                                                    int2* __restrict__ bucketed) {
    __shared__ int cur[NB2];
    const int b = blockIdx.x;
    const int tid = threadIdx.x;
    for (int c = tid; c < NB2; c += 256) cur[c] = bucketBase[c] + ofsT[b * NB2 + c];
    __syncthreads();
    const int e0 = b * EPB;
    const int e1 = min(e0 + EPB, NE);
    for (int i = e0 + tid; i < e1; i += 256) {
        const int d = dst[i];
        const int c = d >> SHIFT;
        const int pos = atomicAdd(&cur[c], 1);
        bucketed[pos] = make_int2(src[i], d & 127);
    }
}

// ---------------- P3: per-bucket CSR (rowptr, dinv, csr_src) + A rescale ----------------
__global__ __launch_bounds__(256) void p3_csr_k(const int2* __restrict__ bucketed,
                                                const int* __restrict__ bucketBase,
                                                int* __restrict__ rowptr,
                                                float* __restrict__ dinv,
                                                int* __restrict__ csr_src,
                                                __half* __restrict__ A) {
    __shared__ int cnt[128];
    __shared__ int excl[128];
    __shared__ float ld[128];
    const int c = blockIdx.x;
    const int tid = threadIdx.x;
    const int base = bucketBase[c];
    const int end = bucketBase[c + 1];
    if (tid < 128) cnt[tid] = 0;
    __syncthreads();
    // phase A: local histogram
    for (int i = base + tid; i < end; i += 256) atomicAdd(&cnt[bucketed[i].y], 1);
    __syncthreads();
    // phase B: scan 128 (Hillis-Steele, guarded), write rowptr + dinv
    if (tid < 128) excl[tid] = cnt[tid];
    __syncthreads();
    for (int off = 1; off < 128; off <<= 1) {
        int a = 0;
        if (tid < 128 && tid >= off) a = excl[tid - off];
        __syncthreads();
        if (tid < 128) excl[tid] += a;
        __syncthreads();
    }
    const int node0 = c << SHIFT;
    if (tid < 128) {
        const int node = node0 + tid;
        const int ex = excl[tid] - cnt[tid];
        if (node < NN) {
            rowptr[node] = base + ex;
            const float dv = rsqrtf((float)cnt[tid] + 1.0f);  // +1 self loop
            dinv[node] = dv;
            ld[tid] = dv;
        }
        excl[tid] = ex;  // becomes the fill cursor
    }
    __syncthreads();
    // phase C: scatter csr_src within this bucket's contiguous window
    for (int i = base + tid; i < end; i += 256) {
        const int2 p = bucketed[i];
        const int pos = atomicAdd(&excl[p.y], 1);
        csr_src[base + pos] = p.x;
    }
    // phase D: rescale A rows by dinv (no dependence on phase C)
    {
        const int node = node0 + (tid >> 1);
        if (node < NN) {
            const float dv = ld[tid >> 1];
            uint4* p = (uint4*)(A + (long)node * 16 + (tid & 1) * 8);
            uint4 v = *p;
            v.x = sc2(v.x, dv); v.y = sc2(v.y, dv);
            v.z = sc2(v.z, dv); v.w = sc2(v.w, dv);
            *p = v;
        }
    }
}

// ---------------- pull-gather, 16 ch fp16: B = dinv*relu(dg*(sum A)+b1) ----------------
__global__ __launch_bounds__(256) void gather16h_k(const int* __restrict__ rowptr,
                                                   const int* __restrict__ csr_src,
                                                   const float* __restrict__ dinv,
                                                   const __half* __restrict__ hs,
                                                   const float* __restrict__ bias,
                                                   __half* __restrict__ outp, int n) {
    const int g = (blockIdx.x * 256 + threadIdx.x) >> 6;
    if (g >= n) return;
    const int lane = threadIdx.x & 63;
    const int q = lane & 3;                 // uint2 chunk within 16-ch row
    const int sub = lane >> 2;              // edge subgroup 0..15
    const float dg = dinv[g];
    const int beg = rowptr[g], end = rowptr[g + 1];
    const uint2* h2p = (const uint2*)hs;
    float a0 = 0.f, a1 = 0.f, a2 = 0.f, a3 = 0.f;
    if (sub == 0) {                          // self term
        uint2 v = h2p[(long)g * 4 + q];
        h2acc(v.x, a0, a1); h2acc(v.y, a2, a3);
    }
    for (int j0 = beg; j0 < end; j0 += 16) {
        int idx = j0 + sub;
        if (idx < end) {
            const int s = csr_src[idx];
            uint2 v = h2p[(long)s * 4 + q];
            h2acc(v.x, a0, a1); h2acc(v.y, a2, a3);
        }
    }
#pragma unroll
    for (int m = 4; m <= 32; m <<= 1) {
        a0 += __shfl_xor(a0, m, 64);
        a1 += __shfl_xor(a1, m, 64);
        a2 += __shfl_xor(a2, m, 64);
        a3 += __shfl_xor(a3, m, 64);
    }
    if (sub == 0) {
        const float4 b = ((const float4*)bias)[q];
        float v0 = fmaxf(fmaf(dg, a0, b.x), 0.0f) * dg;
        float v1 = fmaxf(fmaf(dg, a1, b.y), 0.0f) * dg;
        float v2 = fmaxf(fmaf(dg, a2, b.z), 0.0f) * dg;
        float v3 = fmaxf(fmaf(dg, a3, b.w), 0.0f) * dg;
        uint2 w;
        w.x = packh2(v0, v1);
        w.y = packh2(v2, v3);
        ((uint2*)outp)[(long)g * 4 + q] = w;
    }
}

// ---------------- fused gather16 + gemm2: C = dinv*relu(dg*(sum B)@W2 + b2), fp16 out ----
__global__ __launch_bounds__(256) void g16gemm2h_k(const int* __restrict__ rowptr,
                                                   const int* __restrict__ csr_src,
                                                   const float* __restrict__ dinv,
                                                   const __half* __restrict__ hs,
                                                   const float* __restrict__ W2,
                                                   const float* __restrict__ b2,
                                                   __half* __restrict__ outp, int n) {
    const int lane = threadIdx.x & 63;
    const int wid = blockIdx.x * 4 + (threadIdx.x >> 6);
    const int nWaves = gridDim.x * 4;
    float w2[16];
#pragma unroll
    for (int k = 0; k < 16; ++k) w2[k] = W2[k * 64 + lane];
    const float bm = b2[lane];
    const int q = lane & 3;
    const int sub = lane >> 2;
    const uint2* h2p = (const uint2*)hs;
    for (int g = wid; g < n; g += nWaves) {
        const float dg = dinv[g];
        const int beg = rowptr[g], end = rowptr[g + 1];
        float a0 = 0.f, a1 = 0.f, a2 = 0.f, a3 = 0.f;
        if (sub == 0) {                      // self term
            uint2 v = h2p[(long)g * 4 + q];
            h2acc(v.x, a0, a1); h2acc(v.y, a2, a3);
        }
        for (int j0 = beg; j0 < end; j0 += 16) {
            int idx = j0 + sub;
            if (idx < end) {
                const int s = csr_src[idx];
                uint2 v = h2p[(long)s * 4 + q];
                h2acc(v.x, a0, a1); h2acc(v.y, a2, a3);
            }
        }
#pragma unroll
        for (int m = 4; m <= 32; m <<= 1) {
            a0 += __shfl_xor(a0, m, 64);
            a1 += __shfl_xor(a1, m, 64);
            a2 += __shfl_xor(a2, m, 64);
            a3 += __shfl_xor(a3, m, 64);
        }
        float t = 0.0f;
#pragma unroll
        for (int ql = 0; ql < 4; ++ql) {
            t = fmaf(rdl_f(a0, ql), w2[4 * ql + 0], t);
            t = fmaf(rdl_f(a1, ql), w2[4 * ql + 1], t);
            t = fmaf(rdl_f(a2, ql), w2[4 * ql + 2], t);
            t = fmaf(rdl_f(a3, ql), w2[4 * ql + 3], t);
        }
        float r = fmaxf(fmaf(dg, t, bm), 0.0f);   // dg*(sum)@W2 + b2, relu
        outp[(long)g * 64 + lane] = __float2half(r * dg);  // pre-scaled fp16
    }
}

// ---------------- pull-gather, 64 ch fp16: aggS2 = dg * sum C ----------------
// 8 lanes x uint4 (16B) per 128B row (exactly one cache line per edge).
__global__ __launch_bounds__(256) void gather64h_k(const int* __restrict__ rowptr,
                                                   const int* __restrict__ csr_src,
                                                   const float* __restrict__ dinv,
                                                   const __half* __restrict__ hs,
                                                   float* __restrict__ outp, int n) {
    const int g = (blockIdx.x * 256 + threadIdx.x) >> 6;
    if (g >= n) return;
    const int lane = threadIdx.x & 63;
    const int q = lane & 7;                 // uint4 chunk within 64-ch row
    const int sub = lane >> 3;              // edge subgroup 0..7
    const float dg = dinv[g];
    const int beg = rowptr[g], end = rowptr[g + 1];
    const uint4* h4 = (const uint4*)hs;     // row = 8 chunks of 16B
    float a[8];
#pragma unroll
    for (int i = 0; i < 8; ++i) a[i] = 0.f;
    if (sub == 0) {                          // self term
        uint4 v = h4[(long)g * 8 + q];
        h2acc(v.x, a[0], a[1]); h2acc(v.y, a[2], a[3]);
        h2acc(v.z, a[4], a[5]); h2acc(v.w, a[6], a[7]);
    }
    int j0 = beg;
    for (; j0 + 16 <= end; j0 += 16) {
        const int s0 = csr_src[j0 + sub];
        const int s1 = csr_src[j0 + 8 + sub];
        const uint4 v0 = h4[(long)s0 * 8 + q];
        const uint4 v1 = h4[(long)s1 * 8 + q];
        h2acc(v0.x, a[0], a[1]); h2acc(v0.y, a[2], a[3]);
        h2acc(v0.z, a[4], a[5]); h2acc(v0.w, a[6], a[7]);
        h2acc(v1.x, a[0], a[1]); h2acc(v1.y, a[2], a[3]);
        h2acc(v1.z, a[4], a[5]); h2acc(v1.w, a[6], a[7]);
    }
    for (; j0 < end; j0 += 8) {
        int idx = j0 + sub;
        if (idx < end) {
            const int s = csr_src[idx];
            const uint4 v = h4[(long)s * 8 + q];
            h2acc(v.x, a[0], a[1]); h2acc(v.y, a[2], a[3]);
            h2acc(v.z, a[4], a[5]); h2acc(v.w, a[6], a[7]);
        }
    }
#pragma unroll
    for (int m = 8; m <= 32; m <<= 1) {
#pragma unroll
        for (int i = 0; i < 8; ++i) a[i] += __shfl_xor(a[i], m, 64);
    }
    if (sub == 0) {
        float4* o4 = (float4*)(outp + (long)g * 64 + q * 8);
        o4[0] = make_float4(a[0] * dg, a[1] * dg, a[2] * dg, a[3] * dg);
        o4[1] = make_float4(a[4] * dg, a[5] * dg, a[6] * dg, a[7] * dg);
    }
}

// ---------------- zero-LDS head: W3 in VGPRs, readlane broadcast ----------------
__global__ __launch_bounds__(256) void head_k(const float* __restrict__ aggS2,
                                              const float* __restrict__ W3,
                                              const float* __restrict__ b3,
                                              const float* __restrict__ Wfc,
                                              const float* __restrict__ bfc,
                                              float* __restrict__ out, int n) {
    const int lane = threadIdx.x & 63;
    const int wid = blockIdx.x * 4 + (threadIdx.x >> 6);
    const int nWaves = gridDim.x * 4;
    float w0[64], w1[64];
#pragma unroll
    for (int k = 0; k < 64; ++k) {
        w0[k] = W3[k * 128 + lane];
        w1[k] = W3[k * 128 + lane + 64];
    }
    const float bm0 = b3[lane], bm1 = b3[lane + 64];
    const float wf0 = Wfc[lane], wf1 = Wfc[lane + 64];
    const float bb = bfc[0];
    for (int g0 = wid * 4; g0 < n; g0 += nWaves * 4) {
        const float* base = aggS2 + (long)g0 * 64 + lane;
        const float rv0 = base[0];
        const float rv1 = base[64];
        const float rv2 = base[128];
        const float rv3 = base[192];
        float a00 = 0.f, a01 = 0.f, a10 = 0.f, a11 = 0.f;
        float a20 = 0.f, a21 = 0.f, a30 = 0.f, a31 = 0.f;
#pragma unroll
        for (int k = 0; k < 64; ++k) {
            const float x0 = rdl_f(rv0, k);
            const float x1 = rdl_f(rv1, k);
            const float x2 = rdl_f(rv2, k);
            const float x3 = rdl_f(rv3, k);
            a00 = fmaf(x0, w0[k], a00); a01 = fmaf(x0, w1[k], a01);
            a10 = fmaf(x1, w0[k], a10); a11 = fmaf(x1, w1[k], a11);
            a20 = fmaf(x2, w0[k], a20); a21 = fmaf(x2, w1[k], a21);
            a30 = fmaf(x3, w0[k], a30); a31 = fmaf(x3, w1[k], a31);
        }
        float v0 = fmaxf(a00 + bm0, 0.f) * wf0 + fmaxf(a01 + bm1, 0.f) * wf1;
        float v1 = fmaxf(a10 + bm0, 0.f) * wf0 + fmaxf(a11 + bm1, 0.f) * wf1;
        float v2 = fmaxf(a20 + bm0, 0.f) * wf0 + fmaxf(a21 + bm1, 0.f) * wf1;
        float v3 = fmaxf(a30 + bm0, 0.f) * wf0 + fmaxf(a31 + bm1, 0.f) * wf1;
#pragma unroll
        for (int off = 32; off > 0; off >>= 1) {
            v0 += __shfl_down(v0, off, 64);
            v1 += __shfl_down(v1, off, 64);
            v2 += __shfl_down(v2, off, 64);
            v3 += __shfl_down(v3, off, 64);
        }
        if (lane == 0)
            ((float4*)out)[g0 >> 2] = make_float4(v0 + bb, v1 + bb, v2 + bb, v3 + bb);
    }
}

extern "C" void kernel_launch(void* const* d_in, const int* in_sizes, int n_in,
                              void* d_out, int out_size, void* d_ws, size_t ws_size,
                              hipStream_t stream) {
    const float* x    = (const float*)d_in[0];
    const int*   ei   = (const int*)d_in[1];       // [2,E]: src = ei, dst = ei+E
    const float* W1   = (const float*)d_in[2];
    const float* b1   = (const float*)d_in[3];
    const float* W2   = (const float*)d_in[4];
    const float* b2   = (const float*)d_in[5];
    const float* W3   = (const float*)d_in[6];
    const float* b3   = (const float*)d_in[7];
    const float* Wfc  = (const float*)d_in[8];
    const float* bfc  = (const float*)d_in[9];
    float* out = (float*)d_out;

    const int* src = ei;
    const int* dst = ei + NE;

    // workspace layout (16B-aligned offsets; all in 4B units unless noted):
    // dinv[N] | rowptr[N+8] | mat[NBLK*NB2] | ofsT[NBLK*NB2] | colTotal[1024]
    // | bucketBase[1024] | csr_src[E+64] | bucketed[E] int2
    // | A_h[16N] fp16 | B_h[16N] fp16 | C_h[64N] fp16 | aggS2[64N] f32
    float* dinv       = (float*)d_ws;
    int*   rowptr     = (int*)(dinv + NN);
    int*   mat        = rowptr + NN + 8;
    int*   ofsT       = mat + NBLK * NB2;
    int*   colTotal   = ofsT + NBLK * NB2;
    int*   bucketBase = colTotal + 1024;
    int*   csr_src    = bucketBase + 1024;
    int2*  bucketed   = (int2*)(csr_src + NE + 64);
    __half* A_h       = (__half*)(bucketed + NE);
    __half* B_h       = A_h + (long)NN * 16;
    __half* C_h       = B_h + (long)NN * 16;
    float* aggS2      = (float*)(C_h + (long)NN * 64);

    const int T = 256;

    // ---- CSR build (atomic-free) + gemm1_raw overlapped ----
    const int gemmBlocks = (NN + 15) / 16;             // 6250
    count_gemm1_k<<<NBLK + gemmBlocks, T, 0, stream>>>(dst, mat, x, W1, A_h, NN);
    colscan_k<<<NB2, 64, 0, stream>>>(mat, ofsT, colTotal);
    basescan_k<<<1, 1024, 0, stream>>>(colTotal, bucketBase, rowptr);
    p2_scatter_k<<<NBLK, T, 0, stream>>>(src, dst, ofsT, bucketBase, bucketed);
    p3_csr_k<<<NB2, T, 0, stream>>>(bucketed, bucketBase, rowptr, dinv, csr_src, A_h);

    // ---- B = dinv * relu(dg*(sum A) + b1)  (pre-scaled r1, 16ch fp16) ----
    gather16h_k<<<(NN + 3) / 4, T, 0, stream>>>(rowptr, csr_src, dinv, A_h, b1, B_h, NN);
    // ---- C = dinv * relu(dg*(sum B)@W2 + b2)  (pre-scaled r2, 64ch fp16) ----
    g16gemm2h_k<<<3072, T, 0, stream>>>(rowptr, csr_src, dinv, B_h, W2, b2, C_h, NN);
    // ---- aggS2(64ch f32) = dg * sum C ----
    gather64h_k<<<(NN + 3) / 4, T, 0, stream>>>(rowptr, csr_src, dinv, C_h, aggS2, NN);
    // ---- head: out = relu(aggS2@W3 + b3).Wfc + bfc ----
    head_k<<<2048, T, 0, stream>>>(aggS2, W3, b3, Wfc, bfc, out, NN);
}